// Round 12
// baseline (469.555 us; speedup 1.0000x reference)
//
#include <hip/hip_runtime.h>
#include <math.h>
#include <stdint.h>

// sLSTM cell, B=16384, D=H=1024.
// bf16-MFMA path (needs ws >= ~114 MB):
//   cvt_A: A=[x|h_prev] bf16 [16384][2048]; cvt_W: WT gate-interleaved bf16 [4096][2048],
//   WyT bf16 [1024][1024], bsum f32 [4][1024].
//   gemm_gates / gemm_y: 128x128-tile BK=64 MFMA GEMM (16x16x32), 256 threads (4 waves),
//   LDS 80KB (A dbuf 32K + B tbuf 48K) -> TWO independent blocks per CU: cross-block
//   overlap fills barrier/read/epilogue stalls (m114/m97 mechanism). One barrier +
//   counted vmcnt(4) per K-tile; 16 asm ds_reads in 2 counted-lgkm clusters of 16 MFMA.
//   T2 swizzle both-sides, chained m-tiles, fused gate epilogue.
// Fallback (small ws): round-1 f32 vector kernels.

typedef __attribute__((ext_vector_type(8))) short bf16x8;
typedef __attribute__((ext_vector_type(4))) float f32x4;

constexpr int Bsz = 16384;
constexpr int Dd  = 1024;
constexpr int Hh  = 1024;
constexpr float EPSv = 1e-7f;

__device__ __forceinline__ unsigned short f2bf(float f) {
    union { float f; uint32_t u; } v; v.f = f;
    uint32_t u = v.u + 0x7fffu + ((v.u >> 16) & 1u);   // RNE
    return (unsigned short)(u >> 16);
}

__device__ __forceinline__ void gload16(const void* g, void* l) {
    __builtin_amdgcn_global_load_lds(
        (const __attribute__((address_space(1))) void*)g,
        (__attribute__((address_space(3))) void*)l, 16, 0, 0);
}

__device__ __forceinline__ float sigm_f(float x) { return 1.f / (1.f + __expf(-x)); }
__device__ __forceinline__ float tanh_f(float x) {   // overflow-safe fast tanh
    const float ax = fabsf(x);
    const float t = __expf(-2.f * ax);
    const float r = (1.f - t) / (1.f + t);
    return copysignf(r, x);
}

// inline-asm LDS read (explicit issue order + counted lgkm discipline, rule #18)
#define DSR(d, a, o) asm volatile("ds_read_b128 %0, %1 offset:" o : "=v"(d) : "v"(a) : "memory")
#define LGKM(n) { asm volatile("s_waitcnt lgkmcnt(" #n ")" ::: "memory"); __builtin_amdgcn_sched_barrier(0); }
#define VMC(n)  { asm volatile("s_waitcnt vmcnt(" #n ")" ::: "memory"); __builtin_amdgcn_sched_barrier(0); }

// ---------------- conversion kernels ----------------

__global__ __launch_bounds__(256)
void cvt_A(const float* __restrict__ x, const float* __restrict__ hp, unsigned short* __restrict__ A)
{
    const int idx = blockIdx.x * 256 + threadIdx.x;   // 8 elements each
    const int n = idx * 8;
    const int b = n >> 11, k = n & 2047;
    const float* s = (k < 1024) ? (x + (size_t)b * 1024 + k)
                                : (hp + (size_t)b * 1024 + (k - 1024));
    const float4 v0 = *(const float4*)s;
    const float4 v1 = *(const float4*)(s + 4);
    union { unsigned short u[8]; uint4 v; } pk;
    pk.u[0] = f2bf(v0.x); pk.u[1] = f2bf(v0.y); pk.u[2] = f2bf(v0.z); pk.u[3] = f2bf(v0.w);
    pk.u[4] = f2bf(v1.x); pk.u[5] = f2bf(v1.y); pk.u[6] = f2bf(v1.z); pk.u[7] = f2bf(v1.w);
    *(uint4*)(A + n) = pk.v;
}

// Merged weight-transpose + bias-sum kernel. grid 2308:
//   blocks 0..2303: id = b>>8 selects {Wz,Rz,Wi,Ri,Wf,Rf,Wo,Ro,Wy}; 256 sub-blocks each.
//   blocks 2304..2307: bias sums.
// W/R -> WT[c'][kbase+k], c' = (j&15)|(g<<4)|((j>>4)<<6); Wy -> WyT[j][k].
struct CvtArgs {
    const float* src[9];
    const float* bptr[12];
    unsigned short* wt;
    unsigned short* wyt;
    float* bs;
};

__global__ __launch_bounds__(256)
void cvt_W(CvtArgs P)
{
    __shared__ float tile[64][65];
    const int bid = blockIdx.x;
    const int t = threadIdx.x;
    if (bid >= 2304) {
        const int j = (bid - 2304) * 256 + t;
        P.bs[j]        = P.bptr[0][j] + P.bptr[1][j]  + P.bptr[2][j];
        P.bs[1024 + j] = P.bptr[3][j] + P.bptr[4][j]  + P.bptr[5][j];
        P.bs[2048 + j] = P.bptr[6][j] + P.bptr[7][j]  + P.bptr[8][j];
        P.bs[3072 + j] = P.bptr[9][j] + P.bptr[10][j] + P.bptr[11][j];
        return;
    }
    const int id = bid >> 8, sub = bid & 255;
    const float* __restrict__ src = P.src[id];
    const int kt = sub & 15, jt = sub >> 4;
    {
        const int lr = t >> 4, lc = (t & 15) * 4;
        #pragma unroll
        for (int rr = 0; rr < 64; rr += 16) {
            const float4 v = *(const float4*)(src + (size_t)(kt * 64 + rr + lr) * 1024 + jt * 64 + lc);
            tile[rr + lr][lc + 0] = v.x;
            tile[rr + lr][lc + 1] = v.y;
            tile[rr + lr][lc + 2] = v.z;
            tile[rr + lr][lc + 3] = v.w;
        }
    }
    __syncthreads();
    const int jl = t >> 2, kc = (t & 3) * 16;
    const int j = jt * 64 + jl;
    union { unsigned short u[16]; uint4 v[2]; } pk;
    #pragma unroll
    for (int q = 0; q < 16; ++q) pk.u[q] = f2bf(tile[kc + q][jl]);
    uint4* d;
    if (id == 8) {
        d = (uint4*)(P.wyt + (size_t)j * 1024 + kt * 64 + kc);
    } else {
        const int g = id >> 1, kbase = (id & 1) ? 1024 : 0;
        const int cp = (j & 15) | (g << 4) | ((j >> 4) << 6);
        d = (uint4*)(P.wt + (size_t)cp * 2048 + kbase + kt * 64 + kc);
    }
    d[0] = pk.v[0];
    d[1] = pk.v[1];
}

// ---------------- MFMA GEMM core ----------------
// 256 threads = 4 waves (2 wave-rows x 2 wave-cols). Per-wave output 64x64 = acc[4][4], 16x16x32.
// LDS 80KB: Abuf[2]@0 (2x16KB) + Bbuf[3]@32KB (3x16KB). Tile = [128 rows][64 k] bf16, 128B rows.
// -> 2 independent blocks/CU (launch_bounds(256,2)): decoupled barrier domains overlap.
// Swizzle (T2): 16B chunk c stored at c^(row&7); staged via inverse-swizzled global source +
//   linear global_load_lds dest. Fragment read (16 rows x 4 chunks, 2-way) = conflict-free.
// Per K-tile f (bA=f&1, bB=f%3):
//   VMC(4)  — stgA(f),stgB(f) retired; stgB(f+1) flying   [T4: never 0]
//   s_barrier — WAR + RAW gate
//   stgA(f+1 -> A[bA^1]) 4 gloads ; stgB(f+2 -> B[(f+2)%3]) 4 gloads
//   issue 16 ds_reads [b0,a0,b1,a1] ; LGKM(8) -> 16 MFMA ks0 (b1,a1 drain under)
//   LGKM(0) -> 16 MFMA ks1

template<int LD, int NKT, int NTILES, class Epi>
__device__ void mfma_core(const unsigned short* __restrict__ Ag,
                          const unsigned short* __restrict__ Bg,
                          int m0base, int n0, int t,
                          unsigned short* lds, Epi epi)
{
    constexpr int TOT = NKT * NTILES;
    const int lane = t & 63, wid = t >> 6;
    const int wr = wid >> 1, wc = wid & 1;            // 2M x 2N wave grid
    const int cl = lane & 15, hi = lane >> 4;
    const int Lb = (int)(size_t)(__attribute__((address_space(3))) unsigned short*)lds;
    const int rdA0 = Lb + (wr * 64 + cl) * 128 + ((hi ^ (cl & 7)) << 4);
    const int rdB0 = Lb + 32768 + (wc * 64 + cl) * 128 + ((hi ^ (cl & 7)) << 4);
    const int srow = t >> 3;                          // 0..31
    const int schk = ((t & 7) ^ (srow & 7)) * 8;      // shorts
    const int sdst = t * 16;                          // bytes within 4KB region
    char* const L = (char*)lds;

    auto stgA = [&](int f, int buf) {
        const int ot = f / NKT, kt = f % NKT;
        const unsigned short* g = Ag + (size_t)(m0base + ot * 128 + srow) * LD + kt * 64 + schk;
        char* d = L + buf * 16384 + sdst;
        gload16(g,                  d);
        gload16(g + (size_t)32 * LD, d + 4096);
        gload16(g + (size_t)64 * LD, d + 8192);
        gload16(g + (size_t)96 * LD, d + 12288);
    };
    auto stgB = [&](int f, int buf) {
        const int kt = f % NKT;
        const unsigned short* g = Bg + (size_t)(n0 + srow) * LD + kt * 64 + schk;
        char* d = L + 32768 + buf * 16384 + sdst;
        gload16(g,                  d);
        gload16(g + (size_t)32 * LD, d + 4096);
        gload16(g + (size_t)64 * LD, d + 8192);
        gload16(g + (size_t)96 * LD, d + 12288);
    };

    f32x4 acc[4][4];
    #pragma unroll
    for (int i = 0; i < 4; ++i)
        #pragma unroll
        for (int j = 0; j < 4; ++j) acc[i][j] = (f32x4)0.f;

    // prologue: A(0)->A0, B(0)->B0, B(1)->B1 (12 loads in flight)
    stgA(0, 0); stgB(0, 0); stgB(1, 1);

    int bB = 0;
    for (int f = 0; f < TOT; ++f) {
        const int bA = f & 1;
        const int f1 = (f + 1 < TOT) ? f + 1 : TOT - 1;
        const int f2 = (f + 2 < TOT) ? f + 2 : TOT - 1;
        const int bB2 = (bB >= 1) ? bB - 1 : 2;       // (bB+2)%3

        VMC(4);                                   // A(f),B(f) retired; B(f+1) flying
        __builtin_amdgcn_s_barrier();             // WAR + RAW gate
        stgA(f1, bA ^ 1);
        stgB(f2, bB2);

        const int aof  = rdA0 + (bA << 14);
        const int bof  = rdB0 + bB * 16384;
        const int aof1 = aof ^ 64;
        const int bof1 = bof ^ 64;
        bf16x8 a0[4], b0[4], a1[4], b1[4];

        DSR(b0[0], bof, "0");     DSR(b0[1], bof, "2048");
        DSR(b0[2], bof, "4096");  DSR(b0[3], bof, "6144");
        DSR(a0[0], aof, "0");     DSR(a0[1], aof, "2048");
        DSR(a0[2], aof, "4096");  DSR(a0[3], aof, "6144");
        DSR(b1[0], bof1, "0");    DSR(b1[1], bof1, "2048");
        DSR(b1[2], bof1, "4096"); DSR(b1[3], bof1, "6144");
        DSR(a1[0], aof1, "0");    DSR(a1[1], aof1, "2048");
        DSR(a1[2], aof1, "4096"); DSR(a1[3], aof1, "6144");

        LGKM(8);                                  // b0,a0 ready; b1,a1 draining
        __builtin_amdgcn_s_setprio(1);
        #pragma unroll
        for (int mf = 0; mf < 4; ++mf)
            #pragma unroll
            for (int nf = 0; nf < 4; ++nf)
                acc[mf][nf] = __builtin_amdgcn_mfma_f32_16x16x32_bf16(a0[mf], b0[nf], acc[mf][nf], 0, 0, 0);
        __builtin_amdgcn_s_setprio(0);

        LGKM(0);                                  // b1,a1 ready
        __builtin_amdgcn_s_setprio(1);
        #pragma unroll
        for (int mf = 0; mf < 4; ++mf)
            #pragma unroll
            for (int nf = 0; nf < 4; ++nf)
                acc[mf][nf] = __builtin_amdgcn_mfma_f32_16x16x32_bf16(a1[mf], b1[nf], acc[mf][nf], 0, 0, 0);
        __builtin_amdgcn_s_setprio(0);

        if ((f % NKT) == NKT - 1) {
            epi(f / NKT, acc);
            #pragma unroll
            for (int i = 0; i < 4; ++i)
                #pragma unroll
                for (int j = 0; j < 4; ++j) acc[i][j] = (f32x4)0.f;
        }
        bB = (bB == 2) ? 0 : bB + 1;
    }
    asm volatile("s_waitcnt vmcnt(0)" ::: "memory");  // drain tail junk stages
}

// gates GEMM: A [16384][2048] bf16, WT [4096][2048] bf16 (gate-interleaved cols).
// 128x128 tiles; grid 512 = 2 blocks/CU; each block chains 8 m-tiles at fixed n-panel.
__global__ __launch_bounds__(256, 2)
void gemm_gates(const unsigned short* __restrict__ A, const unsigned short* __restrict__ WT,
                const float* __restrict__ bsum,
                const float* __restrict__ c_prev, const float* __restrict__ n_prev,
                float* __restrict__ out_h, float* __restrict__ out_C, float* __restrict__ out_n,
                unsigned short* __restrict__ h_bf)
{
    __shared__ unsigned short lds[40960];   // 80 KB
    const int t = threadIdx.x;
    const int b = blockIdx.x;               // 512 blocks
    const int nb  = (b & 7) * 4 + (b >> 7);         // 0..31 ; each XCD holds 4 n-panels (2MB L2)
    const int mc  = (b >> 3) & 15;                  // m-chunk 0..15 (8 tiles each)
    const int m0base = mc * 1024;
    const int n0 = nb * 128;                        // c'-space

    const int lane = t & 63, wid = t >> 6;
    const int wr = wid >> 1, wc = wid & 1;
    const int cl = lane & 15, hi = lane >> 4;
    const int j_out = nb * 32 + wc * 16 + cl;       // output column 0..1023
    const float bz_ = bsum[j_out];
    const float bi_ = bsum[1024 + j_out];
    const float bf_ = bsum[2048 + j_out];
    const float bo_ = bsum[3072 + j_out];

    auto epi = [&](int ot, f32x4 (&acc)[4][4]) {
        #pragma unroll
        for (int mf = 0; mf < 4; ++mf) {
            const int rb = m0base + ot * 128 + wr * 64 + mf * 16 + hi * 4;
            #pragma unroll
            for (int r = 0; r < 4; ++r) {
                const size_t idx = (size_t)(rb + r) * 1024 + j_out;
                const float pz = acc[mf][0][r] + bz_;
                const float pi = acc[mf][1][r] + bi_;
                const float pf = acc[mf][2][r] + bf_;
                const float po = acc[mf][3][r] + bo_;
                const float zt = tanh_f(pz);
                const float it = __expf(pi);
                const float ft = sigm_f(pf);
                const float ot_ = sigm_f(po);
                const float Cv = ft * c_prev[idx] + it * zt;
                const float nv = ft * n_prev[idx] + it;
                const float hv = ot_ * tanh_f(Cv / (nv + EPSv));
                out_h[idx] = hv;
                out_C[idx] = Cv;
                out_n[idx] = nv;
                h_bf[idx] = f2bf(hv);
            }
        }
    };

    mfma_core<2048, 32, 8>(A, WT, m0base, n0, t, lds, epi);
}

// y GEMM: h_bf [16384][1024] @ WyT^T + by -> y [16384][1024] f32.
// 128x128 tiles; grid 256; each block chains 4 m-tiles at fixed n-panel.
__global__ __launch_bounds__(256, 2)
void gemm_y(const unsigned short* __restrict__ A, const unsigned short* __restrict__ WyT,
            const float* __restrict__ by, float* __restrict__ y)
{
    __shared__ unsigned short lds[40960];
    const int t = threadIdx.x;
    const int b = blockIdx.x;               // 256 = 32 m-chunks x 8 n-panels
    const int nb = b & 7, mc = b >> 3;
    const int m0base = mc * 512;
    const int n0 = nb * 128;

    const int lane = t & 63, wid = t >> 6;
    const int wr = wid >> 1, wc = wid & 1;
    const int cl = lane & 15, hi = lane >> 4;

    auto epi = [&](int ot, f32x4 (&acc)[4][4]) {
        #pragma unroll
        for (int mf = 0; mf < 4; ++mf) {
            const int rb = m0base + ot * 128 + wr * 64 + mf * 16 + hi * 4;
            #pragma unroll
            for (int nf = 0; nf < 4; ++nf) {
                const int c = n0 + wc * 64 + nf * 16 + cl;
                const float bc = by[c];
                #pragma unroll
                for (int r = 0; r < 4; ++r)
                    y[(size_t)(rb + r) * 1024 + c] = acc[mf][nf][r] + bc;
            }
        }
    };

    mfma_core<1024, 16, 4>(A, WyT, m0base, n0, t, lds, epi);
}

// ---------------- fallback f32 path (round-1 kernels) ----------------

constexpr int FBM = 64, FBN = 64, FBK = 16, FPAD = 4;

__global__ __launch_bounds__(256)
void fb_gates(const float* __restrict__ x, const float* __restrict__ h_prev,
              const float* __restrict__ c_prev, const float* __restrict__ n_prev,
              const float* __restrict__ Wz, const float* __restrict__ Rz,
              const float* __restrict__ Wi, const float* __restrict__ Ri,
              const float* __restrict__ Wf, const float* __restrict__ Rf,
              const float* __restrict__ Wo, const float* __restrict__ Ro,
              const float* __restrict__ bWz, const float* __restrict__ bRz, const float* __restrict__ bz,
              const float* __restrict__ bWi, const float* __restrict__ bRi, const float* __restrict__ bi,
              const float* __restrict__ bWf, const float* __restrict__ bRf, const float* __restrict__ bf_,
              const float* __restrict__ bWo, const float* __restrict__ bRo, const float* __restrict__ bo,
              float* __restrict__ out_h, float* __restrict__ out_C, float* __restrict__ out_n)
{
    __shared__ float sA[FBK][FBM + FPAD];
    __shared__ float sB[4][FBK][FBN + FPAD];
    const int t = threadIdx.x;
    const int col_blk = blockIdx.x & 15, row_blk = blockIdx.x >> 4;
    const int row0 = row_blk * FBM, col0 = col_blk * FBN;
    const int tx = t & 15, ty = t >> 4;
    float acc[4][4][4];
    #pragma unroll
    for (int g = 0; g < 4; ++g)
        for (int i = 0; i < 4; ++i)
            for (int j = 0; j < 4; ++j) acc[g][i][j] = 0.f;
    const int ar = t >> 2, ak = (t & 3) * 4, wk = t >> 4, wcc = (t & 15) * 4;
    for (int phase = 0; phase < 2; ++phase) {
        const float* Am = phase ? h_prev : x;
        const float* W0 = phase ? Rz : Wz; const float* W1 = phase ? Ri : Wi;
        const float* W2 = phase ? Rf : Wf; const float* W3 = phase ? Ro : Wo;
        for (int k0 = 0; k0 < 1024; k0 += FBK) {
            __syncthreads();
            {
                const float4 v = *(const float4*)(Am + (size_t)(row0 + ar) * 1024 + k0 + ak);
                sA[ak + 0][ar] = v.x; sA[ak + 1][ar] = v.y;
                sA[ak + 2][ar] = v.z; sA[ak + 3][ar] = v.w;
            }
            *(float4*)&sB[0][wk][wcc] = *(const float4*)(W0 + (size_t)(k0 + wk) * 1024 + col0 + wcc);
            *(float4*)&sB[1][wk][wcc] = *(const float4*)(W1 + (size_t)(k0 + wk) * 1024 + col0 + wcc);
            *(float4*)&sB[2][wk][wcc] = *(const float4*)(W2 + (size_t)(k0 + wk) * 1024 + col0 + wcc);
            *(float4*)&sB[3][wk][wcc] = *(const float4*)(W3 + (size_t)(k0 + wk) * 1024 + col0 + wcc);
            __syncthreads();
            #pragma unroll
            for (int kk = 0; kk < FBK; ++kk) {
                float a[4], bb[4][4];
                *(float4*)a = *(const float4*)&sA[kk][ty * 4];
                *(float4*)&bb[0][0] = *(const float4*)&sB[0][kk][tx * 4];
                *(float4*)&bb[1][0] = *(const float4*)&sB[1][kk][tx * 4];
                *(float4*)&bb[2][0] = *(const float4*)&sB[2][kk][tx * 4];
                *(float4*)&bb[3][0] = *(const float4*)&sB[3][kk][tx * 4];
                #pragma unroll
                for (int g = 0; g < 4; ++g)
                    for (int i = 0; i < 4; ++i)
                        for (int j = 0; j < 4; ++j)
                            acc[g][i][j] += a[i] * bb[g][j];
            }
        }
    }
    #pragma unroll
    for (int i = 0; i < 4; ++i) {
        const int r = row0 + ty * 4 + i;
        #pragma unroll
        for (int j = 0; j < 4; ++j) {
            const int c = col0 + tx * 4 + j;
            const float pz = acc[0][i][j] + bWz[c] + bRz[c] + bz[c];
            const float pi = acc[1][i][j] + bWi[c] + bRi[c] + bi[c];
            const float pf = acc[2][i][j] + bWf[c] + bRf[c] + bf_[c];
            const float po = acc[3][i][j] + bWo[c] + bRo[c] + bo[c];
            const float zt = tanhf(pz);
            const float it = expf(pi);
            const float ft = 1.f / (1.f + expf(-pf));
            const float ot = 1.f / (1.f + expf(-po));
            const size_t idx = (size_t)r * Hh + c;
            const float Cv = ft * c_prev[idx] + it * zt;
            const float nv = ft * n_prev[idx] + it;
            out_h[idx] = ot * tanhf(Cv / (nv + EPSv));
            out_C[idx] = Cv;
            out_n[idx] = nv;
        }
    }
}

__global__ __launch_bounds__(256)
void fb_ygemm(const float* __restrict__ hmat, const float* __restrict__ Wy,
              const float* __restrict__ by, float* __restrict__ y)
{
    __shared__ float sA[FBK][FBM + FPAD];
    __shared__ float sB[FBK][FBN + FPAD];
    const int t = threadIdx.x;
    const int col_blk = blockIdx.x & 15, row_blk = blockIdx.x >> 4;
    const int row0 = row_blk * FBM, col0 = col_blk * FBN;
    const int tx = t & 15, ty = t >> 4;
    float acc[4][4];
    #pragma unroll
    for (int i = 0; i < 4; ++i)
        for (int j = 0; j < 4; ++j) acc[i][j] = 0.f;
    const int ar = t >> 2, ak = (t & 3) * 4, wk = t >> 4, wcc = (t & 15) * 4;
    for (int k0 = 0; k0 < 1024; k0 += FBK) {
        __syncthreads();
        {
            const float4 v = *(const float4*)(hmat + (size_t)(row0 + ar) * 1024 + k0 + ak);
            sA[ak + 0][ar] = v.x; sA[ak + 1][ar] = v.y;
            sA[ak + 2][ar] = v.z; sA[ak + 3][ar] = v.w;
        }
        *(float4*)&sB[wk][wcc] = *(const float4*)(Wy + (size_t)(k0 + wk) * 1024 + col0 + wcc);
        __syncthreads();
        #pragma unroll
        for (int kk = 0; kk < FBK; ++kk) {
            float a[4], bb[4];
            *(float4*)a = *(const float4*)&sA[kk][ty * 4];
            *(float4*)bb = *(const float4*)&sB[kk][tx * 4];
            #pragma unroll
            for (int i = 0; i < 4; ++i)
                for (int j = 0; j < 4; ++j)
                    acc[i][j] += a[i] * bb[j];
        }
    }
    #pragma unroll
    for (int i = 0; i < 4; ++i) {
        const int r = row0 + ty * 4 + i;
        #pragma unroll
        for (int j = 0; j < 4; ++j) {
            const int c = col0 + tx * 4 + j;
            y[(size_t)r * Dd + c] = acc[i][j] + by[c];
        }
    }
}

// ---------------- launch ----------------

extern "C" void kernel_launch(void* const* d_in, const int* in_sizes, int n_in,
                              void* d_out, int out_size, void* d_ws, size_t ws_size,
                              hipStream_t stream) {
    const float* x      = (const float*)d_in[0];
    const float* h_prev = (const float*)d_in[1];
    const float* c_prev = (const float*)d_in[2];
    const float* n_prev = (const float*)d_in[3];
    const float* Wz  = (const float*)d_in[4];
    const float* bWz = (const float*)d_in[5];
    const float* Rz  = (const float*)d_in[6];
    const float* bRz = (const float*)d_in[7];
    const float* bz  = (const float*)d_in[8];
    const float* Wi  = (const float*)d_in[9];
    const float* bWi = (const float*)d_in[10];
    const float* Ri  = (const float*)d_in[11];
    const float* bRi = (const float*)d_in[12];
    const float* bi  = (const float*)d_in[13];
    const float* Wf  = (const float*)d_in[14];
    const float* bWf = (const float*)d_in[15];
    const float* Rf  = (const float*)d_in[16];
    const float* bRf = (const float*)d_in[17];
    const float* bf_ = (const float*)d_in[18];
    const float* Wo  = (const float*)d_in[19];
    const float* bWo = (const float*)d_in[20];
    const float* Ro  = (const float*)d_in[21];
    const float* bRo = (const float*)d_in[22];
    const float* bo  = (const float*)d_in[23];
    const float* Wy  = (const float*)d_in[24];
    const float* by  = (const float*)d_in[25];

    float* y     = (float*)d_out;
    float* out_h = y + (size_t)Bsz * Dd;
    float* out_C = out_h + (size_t)Bsz * Hh;
    float* out_n = out_C + (size_t)Bsz * Hh;

    // ws layout (bytes)
    const size_t OFF_A    = 0;           // 16384*2048*2 = 67108864
    const size_t OFF_WT   = 67108864;    // 4096*2048*2  = 16777216
    const size_t OFF_WYT  = 83886080;    // 1024*1024*2  = 2097152
    const size_t OFF_HBF  = 85983232;    // 16384*1024*2 = 33554432
    const size_t OFF_BS   = 119537664;   // 4*1024*4     = 16384
    const size_t WS_NEED  = 119554048;

    if (ws_size >= WS_NEED) {
        char* ws = (char*)d_ws;
        unsigned short* A_bf = (unsigned short*)(ws + OFF_A);
        unsigned short* WT   = (unsigned short*)(ws + OFF_WT);
        unsigned short* WyT  = (unsigned short*)(ws + OFF_WYT);
        unsigned short* h_bf = (unsigned short*)(ws + OFF_HBF);
        float* bsum          = (float*)(ws + OFF_BS);

        cvt_A<<<16384, 256, 0, stream>>>(x, h_prev, A_bf);

        CvtArgs P;
        P.src[0] = Wz; P.src[1] = Rz; P.src[2] = Wi; P.src[3] = Ri;
        P.src[4] = Wf; P.src[5] = Rf; P.src[6] = Wo; P.src[7] = Ro; P.src[8] = Wy;
        P.bptr[0] = bWz; P.bptr[1] = bRz; P.bptr[2]  = bz;
        P.bptr[3] = bWi; P.bptr[4] = bRi; P.bptr[5]  = bi;
        P.bptr[6] = bWf; P.bptr[7] = bRf; P.bptr[8]  = bf_;
        P.bptr[9] = bWo; P.bptr[10] = bRo; P.bptr[11] = bo;
        P.wt = WT; P.wyt = WyT; P.bs = bsum;
        cvt_W<<<2308, 256, 0, stream>>>(P);

        gemm_gates<<<512, 256, 0, stream>>>(A_bf, WT, bsum, c_prev, n_prev,
                                            out_h, out_C, out_n, h_bf);
        gemm_y<<<256, 256, 0, stream>>>(h_bf, WyT, by, y);
    } else {
        dim3 block(256);
        dim3 grid((Bsz / FBM) * (Hh / FBN));
        fb_gates<<<grid, block, 0, stream>>>(x, h_prev, c_prev, n_prev,
                                             Wz, Rz, Wi, Ri, Wf, Rf, Wo, Ro,
                                             bWz, bRz, bz, bWi, bRi, bi,
                                             bWf, bRf, bf_, bWo, bRo, bo,
                                             out_h, out_C, out_n);
        fb_ygemm<<<grid, block, 0, stream>>>(out_h, Wy, by, y);
    }
}

// Round 13
// 418.823 us; speedup vs baseline: 1.1211x; 1.1211x over previous
//
#include <hip/hip_runtime.h>
#include <math.h>
#include <stdint.h>

// sLSTM cell, B=16384, D=H=1024.
// bf16-MFMA path (needs ws >= ~114 MB):
//   cvt_all (merged): A=[x|h_prev] bf16 [16384][2048]; WT gate-interleaved bf16
//   [4096][2048]; WyT bf16 [1024][1024]; bsum f32 [4][1024].
//   gemm_gates / gemm_y: 256x256-tile BK=64 MFMA GEMM (16x16x32), A-dbuf + B-tbuf (160KB),
//   ONE barrier + counted vmcnt(4) per K-tile, inline-asm ds_reads with counted lgkm waits,
//   T2 swizzle (0 conflicts), chained m-tiles, fused gate epilogue (nontemporal h/C/n).
// Fallback (small ws): round-1 f32 vector kernels.

typedef __attribute__((ext_vector_type(8))) short bf16x8;
typedef __attribute__((ext_vector_type(4))) float f32x4;

constexpr int Bsz = 16384;
constexpr int Dd  = 1024;
constexpr int Hh  = 1024;
constexpr float EPSv = 1e-7f;

__device__ __forceinline__ unsigned short f2bf(float f) {
    union { float f; uint32_t u; } v; v.f = f;
    uint32_t u = v.u + 0x7fffu + ((v.u >> 16) & 1u);   // RNE
    return (unsigned short)(u >> 16);
}

__device__ __forceinline__ void gload16(const void* g, void* l) {
    __builtin_amdgcn_global_load_lds(
        (const __attribute__((address_space(1))) void*)g,
        (__attribute__((address_space(3))) void*)l, 16, 0, 0);
}

__device__ __forceinline__ float sigm_f(float x) { return 1.f / (1.f + __expf(-x)); }
__device__ __forceinline__ float tanh_f(float x) {   // overflow-safe fast tanh
    const float ax = fabsf(x);
    const float t = __expf(-2.f * ax);
    const float r = (1.f - t) / (1.f + t);
    return copysignf(r, x);
}

// inline-asm LDS read (explicit issue order + counted lgkm discipline, rule #18)
#define DSR(d, a, o) asm volatile("ds_read_b128 %0, %1 offset:" o : "=v"(d) : "v"(a) : "memory")

// ---------------- merged conversion kernel ----------------
// grid 18692:
//   0..16383        : cvt_A (x|h_prev f32 -> A bf16 [16384][2048], 8 elems/thread)
//   16384..18687    : weight transpose (id = (bid-16384)>>8 selects {Wz,Rz,Wi,Ri,Wf,Rf,Wo,Ro,Wy})
//   18688..18691    : bias sums
struct CvtArgs {
    const float* x;
    const float* hp;
    unsigned short* abf;
    const float* src[9];
    const float* bptr[12];
    unsigned short* wt;
    unsigned short* wyt;
    float* bs;
};

__global__ __launch_bounds__(256)
void cvt_all(CvtArgs P)
{
    __shared__ float tile[64][65];
    const int bid = blockIdx.x;
    const int t = threadIdx.x;

    if (bid < 16384) {                     // ---- cvt_A path ----
        const int idx = bid * 256 + t;
        const int n = idx * 8;
        const int b = n >> 11, k = n & 2047;
        const float* s = (k < 1024) ? (P.x + (size_t)b * 1024 + k)
                                    : (P.hp + (size_t)b * 1024 + (k - 1024));
        const float4 v0 = *(const float4*)s;
        const float4 v1 = *(const float4*)(s + 4);
        union { unsigned short u[8]; uint4 v; } pk;
        pk.u[0] = f2bf(v0.x); pk.u[1] = f2bf(v0.y); pk.u[2] = f2bf(v0.z); pk.u[3] = f2bf(v0.w);
        pk.u[4] = f2bf(v1.x); pk.u[5] = f2bf(v1.y); pk.u[6] = f2bf(v1.z); pk.u[7] = f2bf(v1.w);
        *(uint4*)(P.abf + n) = pk.v;
        return;
    }
    if (bid >= 18688) {                    // ---- bias path ----
        const int j = (bid - 18688) * 256 + t;
        P.bs[j]        = P.bptr[0][j] + P.bptr[1][j]  + P.bptr[2][j];
        P.bs[1024 + j] = P.bptr[3][j] + P.bptr[4][j]  + P.bptr[5][j];
        P.bs[2048 + j] = P.bptr[6][j] + P.bptr[7][j]  + P.bptr[8][j];
        P.bs[3072 + j] = P.bptr[9][j] + P.bptr[10][j] + P.bptr[11][j];
        return;
    }
    // ---- weight transpose path ----
    const int wb = bid - 16384;
    const int id = wb >> 8, sub = wb & 255;
    const float* __restrict__ src = P.src[id];
    const int kt = sub & 15, jt = sub >> 4;
    {
        const int lr = t >> 4, lc = (t & 15) * 4;
        #pragma unroll
        for (int rr = 0; rr < 64; rr += 16) {
            const float4 v = *(const float4*)(src + (size_t)(kt * 64 + rr + lr) * 1024 + jt * 64 + lc);
            tile[rr + lr][lc + 0] = v.x;
            tile[rr + lr][lc + 1] = v.y;
            tile[rr + lr][lc + 2] = v.z;
            tile[rr + lr][lc + 3] = v.w;
        }
    }
    __syncthreads();
    const int jl = t >> 2, kc = (t & 3) * 16;
    const int j = jt * 64 + jl;
    union { unsigned short u[16]; uint4 v[2]; } pk;
    #pragma unroll
    for (int q = 0; q < 16; ++q) pk.u[q] = f2bf(tile[kc + q][jl]);
    uint4* d;
    if (id == 8) {
        d = (uint4*)(P.wyt + (size_t)j * 1024 + kt * 64 + kc);
    } else {
        const int g = id >> 1, kbase = (id & 1) ? 1024 : 0;
        const int cp = (j & 15) | (g << 4) | ((j >> 4) << 6);
        d = (uint4*)(P.wt + (size_t)cp * 2048 + kbase + kt * 64 + kc);
    }
    d[0] = pk.v[0];
    d[1] = pk.v[1];
}

// ---------------- MFMA GEMM core (R8-proven) ----------------
// 512 threads = 8 waves (2 wave-rows x 4 wave-cols). Per-wave output 128x64 = acc[8][4], 16x16x32.
// LDS 160KB: Abuf[2]@0 (2x32KB) + Bbuf[3]@64KB (3x32KB). Tile = [256 rows][64 k] bf16, 128B rows.
// Swizzle (T2): 16B chunk c stored at c^(row&7); staged via inverse-swizzled global source +
//   linear global_load_lds dest (rule #21). Fragment read (16 rows x 4 chunks) = 0 conflicts.
// Per K-tile f:
//   vmcnt(4) — A(f),B(f) retired (B(f+1) flying; T4 never 0) | s_barrier (WAR+RAW gate)
//   stage A(f+1), B(f+2)  (8 gloads)
//   20 asm ds_read (a0[8],b0[4],a1[8]) ; lgkm(8)+SB0 -> 32 MFMA ks0 (a1 drains underneath)
//   4 asm ds_read (b1) ; lgkm(0)+SB0 -> 32 MFMA ks1

template<int LD, int NTK, int NTILES, class Epi>
__device__ void mfma_core(const unsigned short* __restrict__ Ag,
                          const unsigned short* __restrict__ Bg,
                          int m0base, int n0, int t,
                          unsigned short* lds, Epi epi)
{
    constexpr int TOT = NTK * NTILES;
    const int lane = t & 63, wid = t >> 6;
    const int wr = wid >> 2, wc = wid & 3;            // 2M x 4N wave grid
    const int cl = lane & 15, hi = lane >> 4;
    const int Lb = (int)(size_t)(__attribute__((address_space(3))) unsigned short*)lds;
    const int rdA0 = Lb + (wr * 128 + cl) * 128 + ((hi ^ (cl & 7)) << 4);
    const int rdB0 = Lb + 65536 + (wc * 64 + cl) * 128 + ((hi ^ (cl & 7)) << 4);
    const int srow = t >> 3;
    const int schk = ((t & 7) ^ (srow & 7)) * 8;      // shorts
    const int sdst = t * 16;                          // bytes
    char* const L = (char*)lds;

    auto stgA = [&](int f, int buf) {
        const int ot = f / NTK, kt = f % NTK;
        const unsigned short* g = Ag + (size_t)(m0base + ot * 256 + srow) * LD + kt * 64 + schk;
        char* d = L + buf * 32768 + sdst;
        gload16(g,                  d);
        gload16(g + (size_t) 64 * LD, d + 8192);
        gload16(g + (size_t)128 * LD, d + 16384);
        gload16(g + (size_t)192 * LD, d + 24576);
    };
    auto stgB = [&](int f, int buf) {
        const int kt = f % NTK;
        const unsigned short* g = Bg + (size_t)(n0 + srow) * LD + kt * 64 + schk;
        char* d = L + 65536 + buf * 32768 + sdst;
        gload16(g,                  d);
        gload16(g + (size_t) 64 * LD, d + 8192);
        gload16(g + (size_t)128 * LD, d + 16384);
        gload16(g + (size_t)192 * LD, d + 24576);
    };

    f32x4 acc[8][4];
    #pragma unroll
    for (int i = 0; i < 8; ++i)
        #pragma unroll
        for (int j = 0; j < 4; ++j) acc[i][j] = (f32x4)0.f;

    // prologue: A(0)->A0, B(0)->B0, B(1)->B1 (12 loads in flight)
    stgA(0, 0); stgB(0, 0); stgB(1, 1);

    int bA = 0, bB = 0;
    for (int f = 0; f < TOT; ++f) {
        const int f1 = (f + 1 < TOT) ? f + 1 : TOT - 1;
        const int f2 = (f + 2 < TOT) ? f + 2 : TOT - 1;
        const int bB2 = (bB >= 1) ? bB - 1 : 2;       // (bB+2)%3

        asm volatile("s_waitcnt vmcnt(4)" ::: "memory");   // A(f),B(f) retired; B(f+1) flying
        __builtin_amdgcn_s_barrier();                      // WAR + RAW gate
        stgA(f1, bA ^ 1);
        stgB(f2, bB2);

        const int aof  = rdA0 + (bA << 15);
        const int bof  = rdB0 + (bB << 15);
        const int aof1 = aof ^ 64;
        const int bof1 = bof ^ 64;
        bf16x8 a0[8], b0[4], a1[8], b1[4];

        DSR(a0[0], aof, "0");     DSR(a0[1], aof, "2048");
        DSR(a0[2], aof, "4096");  DSR(a0[3], aof, "6144");
        DSR(a0[4], aof, "8192");  DSR(a0[5], aof, "10240");
        DSR(a0[6], aof, "12288"); DSR(a0[7], aof, "14336");
        DSR(b0[0], bof, "0");     DSR(b0[1], bof, "2048");
        DSR(b0[2], bof, "4096");  DSR(b0[3], bof, "6144");
        DSR(a1[0], aof1, "0");     DSR(a1[1], aof1, "2048");
        DSR(a1[2], aof1, "4096");  DSR(a1[3], aof1, "6144");
        DSR(a1[4], aof1, "8192");  DSR(a1[5], aof1, "10240");
        DSR(a1[6], aof1, "12288"); DSR(a1[7], aof1, "14336");

        asm volatile("s_waitcnt lgkmcnt(8)" ::: "memory");  // a0,b0 ready; a1 still draining
        __builtin_amdgcn_sched_barrier(0);
        __builtin_amdgcn_s_setprio(1);
        #pragma unroll
        for (int mf = 0; mf < 8; ++mf)
            #pragma unroll
            for (int nf = 0; nf < 4; ++nf)
                acc[mf][nf] = __builtin_amdgcn_mfma_f32_16x16x32_bf16(a0[mf], b0[nf], acc[mf][nf], 0, 0, 0);

        DSR(b1[0], bof1, "0");    DSR(b1[1], bof1, "2048");
        DSR(b1[2], bof1, "4096"); DSR(b1[3], bof1, "6144");

        asm volatile("s_waitcnt lgkmcnt(0)" ::: "memory");  // a1,b1 ready
        __builtin_amdgcn_sched_barrier(0);
        #pragma unroll
        for (int mf = 0; mf < 8; ++mf)
            #pragma unroll
            for (int nf = 0; nf < 4; ++nf)
                acc[mf][nf] = __builtin_amdgcn_mfma_f32_16x16x32_bf16(a1[mf], b1[nf], acc[mf][nf], 0, 0, 0);
        __builtin_amdgcn_s_setprio(0);

        if ((f % NTK) == NTK - 1) {
            epi(f / NTK, acc);
            #pragma unroll
            for (int i = 0; i < 8; ++i)
                #pragma unroll
                for (int j = 0; j < 4; ++j) acc[i][j] = (f32x4)0.f;
        }
        bA ^= 1;
        bB = (bB == 2) ? 0 : bB + 1;
    }
    asm volatile("s_waitcnt vmcnt(0)" ::: "memory");  // drain tail junk stages
}

// gates GEMM: A [16384][2048] bf16, WT [4096][2048] bf16 (gate-interleaved cols).
// grid 256 = 1 block/CU; each block chains 4 m-tiles at fixed n-panel.
__global__ __launch_bounds__(512, 2)
void gemm_gates(const unsigned short* __restrict__ A, const unsigned short* __restrict__ WT,
                const float* __restrict__ bsum,
                const float* __restrict__ c_prev, const float* __restrict__ n_prev,
                float* __restrict__ out_h, float* __restrict__ out_C, float* __restrict__ out_n,
                unsigned short* __restrict__ h_bf)
{
    __shared__ unsigned short lds[81920];   // 160 KB
    const int t = threadIdx.x;
    const int b = blockIdx.x;               // 256 blocks
    const int nb  = (b & 7) * 2 + (b >> 7);         // 0..15 ; each XCD holds 2 n-panels in L2
    const int mb0 = ((b >> 3) & 15) * 4;            // m-tiles mb0..mb0+3
    const int m0base = mb0 * 256;
    const int n0 = nb * 256;                        // c'-space

    const int lane = t & 63, wid = t >> 6;
    const int wr = wid >> 2, wc = wid & 3;
    const int cl = lane & 15, hi = lane >> 4;
    const int j_out = nb * 64 + wc * 16 + cl;       // output column 0..1023
    const float bz_ = bsum[j_out];
    const float bi_ = bsum[1024 + j_out];
    const float bf_ = bsum[2048 + j_out];
    const float bo_ = bsum[3072 + j_out];

    auto epi = [&](int ot, f32x4 (&acc)[8][4]) {
        #pragma unroll
        for (int mf = 0; mf < 8; ++mf) {
            const int rb = m0base + ot * 256 + wr * 128 + mf * 16 + hi * 4;
            #pragma unroll
            for (int r = 0; r < 4; ++r) {
                const size_t idx = (size_t)(rb + r) * 1024 + j_out;
                const float pz = acc[mf][0][r] + bz_;
                const float pi = acc[mf][1][r] + bi_;
                const float pf = acc[mf][2][r] + bf_;
                const float po = acc[mf][3][r] + bo_;
                const float zt = tanh_f(pz);
                const float it = __expf(pi);
                const float ft = sigm_f(pf);
                const float ot_ = sigm_f(po);
                const float Cv = ft * c_prev[idx] + it * zt;
                const float nv = ft * n_prev[idx] + it;
                const float hv = ot_ * tanh_f(Cv / (nv + EPSv));
                __builtin_nontemporal_store(hv, &out_h[idx]);   // write-once: keep out of L2
                __builtin_nontemporal_store(Cv, &out_C[idx]);
                __builtin_nontemporal_store(nv, &out_n[idx]);
                h_bf[idx] = f2bf(hv);                           // re-read by gemm_y: cached
            }
        }
    };

    mfma_core<2048, 32, 4>(A, WT, m0base, n0, t, lds, epi);
}

// y GEMM: h_bf [16384][1024] @ WyT^T + by -> y [16384][1024] f32. grid 256, 1 tile/block.
__global__ __launch_bounds__(512, 2)
void gemm_y(const unsigned short* __restrict__ A, const unsigned short* __restrict__ WyT,
            const float* __restrict__ by, float* __restrict__ y)
{
    __shared__ unsigned short lds[81920];
    const int t = threadIdx.x;
    const int b = blockIdx.x;               // 256 = 64 mb x 4 nb
    const int nb = b & 3, mb = b >> 2;
    const int m0base = mb * 256, n0 = nb * 256;

    const int lane = t & 63, wid = t >> 6;
    const int wr = wid >> 2, wc = wid & 3;
    const int cl = lane & 15, hi = lane >> 4;

    auto epi = [&](int ot, f32x4 (&acc)[8][4]) {
        (void)ot;
        #pragma unroll
        for (int mf = 0; mf < 8; ++mf) {
            const int rb = m0base + wr * 128 + mf * 16 + hi * 4;
            #pragma unroll
            for (int nf = 0; nf < 4; ++nf) {
                const int c = n0 + wc * 64 + nf * 16 + cl;
                const float bc = by[c];
                #pragma unroll
                for (int r = 0; r < 4; ++r)
                    __builtin_nontemporal_store(acc[mf][nf][r] + bc, &y[(size_t)(rb + r) * 1024 + c]);
            }
        }
    };

    mfma_core<1024, 16, 1>(A, WyT, m0base, n0, t, lds, epi);
}

// ---------------- fallback f32 path (round-1 kernels) ----------------

constexpr int FBM = 64, FBN = 64, FBK = 16, FPAD = 4;

__global__ __launch_bounds__(256)
void fb_gates(const float* __restrict__ x, const float* __restrict__ h_prev,
              const float* __restrict__ c_prev, const float* __restrict__ n_prev,
              const float* __restrict__ Wz, const float* __restrict__ Rz,
              const float* __restrict__ Wi, const float* __restrict__ Ri,
              const float* __restrict__ Wf, const float* __restrict__ Rf,
              const float* __restrict__ Wo, const float* __restrict__ Ro,
              const float* __restrict__ bWz, const float* __restrict__ bRz, const float* __restrict__ bz,
              const float* __restrict__ bWi, const float* __restrict__ bRi, const float* __restrict__ bi,
              const float* __restrict__ bWf, const float* __restrict__ bRf, const float* __restrict__ bf_,
              const float* __restrict__ bWo, const float* __restrict__ bRo, const float* __restrict__ bo,
              float* __restrict__ out_h, float* __restrict__ out_C, float* __restrict__ out_n)
{
    __shared__ float sA[FBK][FBM + FPAD];
    __shared__ float sB[4][FBK][FBN + FPAD];
    const int t = threadIdx.x;
    const int col_blk = blockIdx.x & 15, row_blk = blockIdx.x >> 4;
    const int row0 = row_blk * FBM, col0 = col_blk * FBN;
    const int tx = t & 15, ty = t >> 4;
    float acc[4][4][4];
    #pragma unroll
    for (int g = 0; g < 4; ++g)
        for (int i = 0; i < 4; ++i)
            for (int j = 0; j < 4; ++j) acc[g][i][j] = 0.f;
    const int ar = t >> 2, ak = (t & 3) * 4, wk = t >> 4, wcc = (t & 15) * 4;
    for (int phase = 0; phase < 2; ++phase) {
        const float* Am = phase ? h_prev : x;
        const float* W0 = phase ? Rz : Wz; const float* W1 = phase ? Ri : Wi;
        const float* W2 = phase ? Rf : Wf; const float* W3 = phase ? Ro : Wo;
        for (int k0 = 0; k0 < 1024; k0 += FBK) {
            __syncthreads();
            {
                const float4 v = *(const float4*)(Am + (size_t)(row0 + ar) * 1024 + k0 + ak);
                sA[ak + 0][ar] = v.x; sA[ak + 1][ar] = v.y;
                sA[ak + 2][ar] = v.z; sA[ak + 3][ar] = v.w;
            }
            *(float4*)&sB[0][wk][wcc] = *(const float4*)(W0 + (size_t)(k0 + wk) * 1024 + col0 + wcc);
            *(float4*)&sB[1][wk][wcc] = *(const float4*)(W1 + (size_t)(k0 + wk) * 1024 + col0 + wcc);
            *(float4*)&sB[2][wk][wcc] = *(const float4*)(W2 + (size_t)(k0 + wk) * 1024 + col0 + wcc);
            *(float4*)&sB[3][wk][wcc] = *(const float4*)(W3 + (size_t)(k0 + wk) * 1024 + col0 + wcc);
            __syncthreads();
            #pragma unroll
            for (int kk = 0; kk < FBK; ++kk) {
                float a[4], bb[4][4];
                *(float4*)a = *(const float4*)&sA[kk][ty * 4];
                *(float4*)&bb[0][0] = *(const float4*)&sB[0][kk][tx * 4];
                *(float4*)&bb[1][0] = *(const float4*)&sB[1][kk][tx * 4];
                *(float4*)&bb[2][0] = *(const float4*)&sB[2][kk][tx * 4];
                *(float4*)&bb[3][0] = *(const float4*)&sB[3][kk][tx * 4];
                #pragma unroll
                for (int g = 0; g < 4; ++g)
                    for (int i = 0; i < 4; ++i)
                        for (int j = 0; j < 4; ++j)
                            acc[g][i][j] += a[i] * bb[g][j];
            }
        }
    }
    #pragma unroll
    for (int i = 0; i < 4; ++i) {
        const int r = row0 + ty * 4 + i;
        #pragma unroll
        for (int j = 0; j < 4; ++j) {
            const int c = col0 + tx * 4 + j;
            const float pz = acc[0][i][j] + bWz[c] + bRz[c] + bz[c];
            const float pi = acc[1][i][j] + bWi[c] + bRi[c] + bi[c];
            const float pf = acc[2][i][j] + bWf[c] + bRf[c] + bf_[c];
            const float po = acc[3][i][j] + bWo[c] + bRo[c] + bo[c];
            const float zt = tanhf(pz);
            const float it = expf(pi);
            const float ft = 1.f / (1.f + expf(-pf));
            const float ot = 1.f / (1.f + expf(-po));
            const size_t idx = (size_t)r * Hh + c;
            const float Cv = ft * c_prev[idx] + it * zt;
            const float nv = ft * n_prev[idx] + it;
            out_h[idx] = ot * tanhf(Cv / (nv + EPSv));
            out_C[idx] = Cv;
            out_n[idx] = nv;
        }
    }
}

__global__ __launch_bounds__(256)
void fb_ygemm(const float* __restrict__ hmat, const float* __restrict__ Wy,
              const float* __restrict__ by, float* __restrict__ y)
{
    __shared__ float sA[FBK][FBM + FPAD];
    __shared__ float sB[FBK][FBN + FPAD];
    const int t = threadIdx.x;
    const int col_blk = blockIdx.x & 15, row_blk = blockIdx.x >> 4;
    const int row0 = row_blk * FBM, col0 = col_blk * FBN;
    const int tx = t & 15, ty = t >> 4;
    float acc[4][4];
    #pragma unroll
    for (int i = 0; i < 4; ++i)
        for (int j = 0; j < 4; ++j) acc[i][j] = 0.f;
    const int ar = t >> 2, ak = (t & 3) * 4, wk = t >> 4, wcc = (t & 15) * 4;
    for (int k0 = 0; k0 < 1024; k0 += FBK) {
        __syncthreads();
        {
            const float4 v = *(const float4*)(hmat + (size_t)(row0 + ar) * 1024 + k0 + ak);
            sA[ak + 0][ar] = v.x; sA[ak + 1][ar] = v.y;
            sA[ak + 2][ar] = v.z; sA[ak + 3][ar] = v.w;
        }
        *(float4*)&sB[wk][wcc] = *(const float4*)(Wy + (size_t)(k0 + wk) * 1024 + col0 + wcc);
        __syncthreads();
        #pragma unroll
        for (int kk = 0; kk < FBK; ++kk) {
            float a[4], bb[4];
            *(float4*)a = *(const float4*)&sA[kk][ty * 4];
            *(float4*)bb = *(const float4*)&sB[kk][tx * 4];
            #pragma unroll
            for (int i = 0; i < 4; ++i)
                for (int j = 0; j < 4; ++j)
                    acc[i][j] += a[i] * bb[j];
        }
    }
    #pragma unroll
    for (int i = 0; i < 4; ++i) {
        const int r = row0 + ty * 4 + i;
        #pragma unroll
        for (int j = 0; j < 4; ++j) {
            const int c = col0 + tx * 4 + j;
            y[(size_t)r * Dd + c] = acc[i][j] + by[c];
        }
    }
}

// ---------------- launch ----------------

extern "C" void kernel_launch(void* const* d_in, const int* in_sizes, int n_in,
                              void* d_out, int out_size, void* d_ws, size_t ws_size,
                              hipStream_t stream) {
    const float* x      = (const float*)d_in[0];
    const float* h_prev = (const float*)d_in[1];
    const float* c_prev = (const float*)d_in[2];
    const float* n_prev = (const float*)d_in[3];
    const float* Wz  = (const float*)d_in[4];
    const float* bWz = (const float*)d_in[5];
    const float* Rz  = (const float*)d_in[6];
    const float* bRz = (const float*)d_in[7];
    const float* bz  = (const float*)d_in[8];
    const float* Wi  = (const float*)d_in[9];
    const float* bWi = (const float*)d_in[10];
    const float* Ri  = (const float*)d_in[11];
    const float* bRi = (const float*)d_in[12];
    const float* bi  = (const float*)d_in[13];
    const float* Wf  = (const float*)d_in[14];
    const float* bWf = (const float*)d_in[15];
    const float* Rf  = (const float*)d_in[16];
    const float* bRf = (const float*)d_in[17];
    const float* bf_ = (const float*)d_in[18];
    const float* Wo  = (const float*)d_in[19];
    const float* bWo = (const float*)d_in[20];
    const float* Ro  = (const float*)d_in[21];
    const float* bRo = (const float*)d_in[22];
    const float* bo  = (const float*)d_in[23];
    const float* Wy  = (const float*)d_in[24];
    const float* by  = (const float*)d_in[25];

    float* y     = (float*)d_out;
    float* out_h = y + (size_t)Bsz * Dd;
    float* out_C = out_h + (size_t)Bsz * Hh;
    float* out_n = out_C + (size_t)Bsz * Hh;

    // ws layout (bytes)
    const size_t OFF_A    = 0;           // 16384*2048*2 = 67108864
    const size_t OFF_WT   = 67108864;    // 4096*2048*2  = 16777216
    const size_t OFF_WYT  = 83886080;    // 1024*1024*2  = 2097152
    const size_t OFF_HBF  = 85983232;    // 16384*1024*2 = 33554432
    const size_t OFF_BS   = 119537664;   // 4*1024*4     = 16384
    const size_t WS_NEED  = 119554048;

    if (ws_size >= WS_NEED) {
        char* ws = (char*)d_ws;
        unsigned short* A_bf = (unsigned short*)(ws + OFF_A);
        unsigned short* WT   = (unsigned short*)(ws + OFF_WT);
        unsigned short* WyT  = (unsigned short*)(ws + OFF_WYT);
        unsigned short* h_bf = (unsigned short*)(ws + OFF_HBF);
        float* bsum          = (float*)(ws + OFF_BS);

        CvtArgs P;
        P.x = x; P.hp = h_prev; P.abf = A_bf;
        P.src[0] = Wz; P.src[1] = Rz; P.src[2] = Wi; P.src[3] = Ri;
        P.src[4] = Wf; P.src[5] = Rf; P.src[6] = Wo; P.src[7] = Ro; P.src[8] = Wy;
        P.bptr[0] = bWz; P.bptr[1] = bRz; P.bptr[2]  = bz;
        P.bptr[3] = bWi; P.bptr[4] = bRi; P.bptr[5]  = bi;
        P.bptr[6] = bWf; P.bptr[7] = bRf; P.bptr[8]  = bf_;
        P.bptr[9] = bWo; P.bptr[10] = bRo; P.bptr[11] = bo;
        P.wt = WT; P.wyt = WyT; P.bs = bsum;
        cvt_all<<<18692, 256, 0, stream>>>(P);

        gemm_gates<<<256, 512, 0, stream>>>(A_bf, WT, bsum, c_prev, n_prev,
                                            out_h, out_C, out_n, h_bf);
        gemm_y<<<256, 512, 0, stream>>>(h_bf, WyT, by, y);
    } else {
        dim3 block(256);
        dim3 grid((Bsz / FBM) * (Hh / FBN));
        fb_gates<<<grid, block, 0, stream>>>(x, h_prev, c_prev, n_prev,
                                             Wz, Rz, Wi, Ri, Wf, Rf, Wo, Ro,
                                             bWz, bRz, bz, bWi, bRi, bi,
                                             bWf, bRf, bf_, bWo, bRo, bo,
                                             out_h, out_C, out_n);
        fb_ygemm<<<grid, block, 0, stream>>>(out_h, Wy, by, y);
    }
}

// Round 14
// 411.147 us; speedup vs baseline: 1.1421x; 1.0187x over previous
//
#include <hip/hip_runtime.h>
#include <math.h>
#include <stdint.h>

// sLSTM cell, B=16384, D=H=1024.
// bf16-MFMA path (needs ws >= ~114 MB):
//   cvt_all (merged): A=[x|h_prev] bf16 [16384][2048]; WT gate-interleaved bf16
//   [4096][2048]; WyT bf16 [1024][1024]; bsum f32 [4][1024].
//   gemm_gates / gemm_y: m201-style 8-phase 256x256-tile BK=64 MFMA GEMM (16x16x32),
//   2x double-buffered LDS (128KB), precomputed loop-invariant LDS base registers
//   (zero per-phase address VALU), asm ds_reads drain during barrier wait,
//   vmcnt(4) only at P4/P8 (T4), T2 swizzle (0 conflicts), B-frag register caching
//   across mh-halves, chained m-tiles, fused nontemporal gate epilogue.
// Fallback (small ws): round-1 f32 vector kernels.

typedef __attribute__((ext_vector_type(8))) short bf16x8;
typedef __attribute__((ext_vector_type(4))) float f32x4;

constexpr int Bsz = 16384;
constexpr int Dd  = 1024;
constexpr int Hh  = 1024;
constexpr float EPSv = 1e-7f;

__device__ __forceinline__ unsigned short f2bf(float f) {
    union { float f; uint32_t u; } v; v.f = f;
    uint32_t u = v.u + 0x7fffu + ((v.u >> 16) & 1u);   // RNE
    return (unsigned short)(u >> 16);
}

__device__ __forceinline__ void gload16(const void* g, void* l) {
    __builtin_amdgcn_global_load_lds(
        (const __attribute__((address_space(1))) void*)g,
        (__attribute__((address_space(3))) void*)l, 16, 0, 0);
}

__device__ __forceinline__ float sigm_f(float x) { return 1.f / (1.f + __expf(-x)); }
__device__ __forceinline__ float tanh_f(float x) {   // overflow-safe fast tanh
    const float ax = fabsf(x);
    const float t = __expf(-2.f * ax);
    const float r = (1.f - t) / (1.f + t);
    return copysignf(r, x);
}

#define DSR(d, a, o) asm volatile("ds_read_b128 %0, %1 offset:" o : "=v"(d) : "v"(a) : "memory")
#define LGKM0() { asm volatile("s_waitcnt lgkmcnt(0)" ::: "memory"); __builtin_amdgcn_sched_barrier(0); }
#define VMC(n)  { asm volatile("s_waitcnt vmcnt(" #n ")" ::: "memory"); __builtin_amdgcn_sched_barrier(0); }
#define BAR()   __builtin_amdgcn_s_barrier()

// ---------------- merged conversion kernel ----------------
// grid 18692: 0..16383 cvt_A ; 16384..18687 weight transpose ; 18688..18691 bias sums
struct CvtArgs {
    const float* x;
    const float* hp;
    unsigned short* abf;
    const float* src[9];
    const float* bptr[12];
    unsigned short* wt;
    unsigned short* wyt;
    float* bs;
};

__global__ __launch_bounds__(256)
void cvt_all(CvtArgs P)
{
    __shared__ float tile[64][65];
    const int bid = blockIdx.x;
    const int t = threadIdx.x;

    if (bid < 16384) {                     // ---- cvt_A path ----
        const int idx = bid * 256 + t;
        const int n = idx * 8;
        const int b = n >> 11, k = n & 2047;
        const float* s = (k < 1024) ? (P.x + (size_t)b * 1024 + k)
                                    : (P.hp + (size_t)b * 1024 + (k - 1024));
        const float4 v0 = *(const float4*)s;
        const float4 v1 = *(const float4*)(s + 4);
        union { unsigned short u[8]; uint4 v; } pk;
        pk.u[0] = f2bf(v0.x); pk.u[1] = f2bf(v0.y); pk.u[2] = f2bf(v0.z); pk.u[3] = f2bf(v0.w);
        pk.u[4] = f2bf(v1.x); pk.u[5] = f2bf(v1.y); pk.u[6] = f2bf(v1.z); pk.u[7] = f2bf(v1.w);
        *(uint4*)(P.abf + n) = pk.v;
        return;
    }
    if (bid >= 18688) {                    // ---- bias path ----
        const int j = (bid - 18688) * 256 + t;
        P.bs[j]        = P.bptr[0][j] + P.bptr[1][j]  + P.bptr[2][j];
        P.bs[1024 + j] = P.bptr[3][j] + P.bptr[4][j]  + P.bptr[5][j];
        P.bs[2048 + j] = P.bptr[6][j] + P.bptr[7][j]  + P.bptr[8][j];
        P.bs[3072 + j] = P.bptr[9][j] + P.bptr[10][j] + P.bptr[11][j];
        return;
    }
    // ---- weight transpose path ----
    const int wb = bid - 16384;
    const int id = wb >> 8, sub = wb & 255;
    const float* __restrict__ src = P.src[id];
    const int kt = sub & 15, jt = sub >> 4;
    {
        const int lr = t >> 4, lc = (t & 15) * 4;
        #pragma unroll
        for (int rr = 0; rr < 64; rr += 16) {
            const float4 v = *(const float4*)(src + (size_t)(kt * 64 + rr + lr) * 1024 + jt * 64 + lc);
            tile[rr + lr][lc + 0] = v.x;
            tile[rr + lr][lc + 1] = v.y;
            tile[rr + lr][lc + 2] = v.z;
            tile[rr + lr][lc + 3] = v.w;
        }
    }
    __syncthreads();
    const int jl = t >> 2, kc = (t & 3) * 16;
    const int j = jt * 64 + jl;
    union { unsigned short u[16]; uint4 v[2]; } pk;
    #pragma unroll
    for (int q = 0; q < 16; ++q) pk.u[q] = f2bf(tile[kc + q][jl]);
    uint4* d;
    if (id == 8) {
        d = (uint4*)(P.wyt + (size_t)j * 1024 + kt * 64 + kc);
    } else {
        const int g = id >> 1, kbase = (id & 1) ? 1024 : 0;
        const int cp = (j & 15) | (g << 4) | ((j >> 4) << 6);
        d = (uint4*)(P.wt + (size_t)cp * 2048 + kbase + kt * 64 + kc);
    }
    d[0] = pk.v[0];
    d[1] = pk.v[1];
}

// ---------------- 8-phase MFMA GEMM core ----------------
// 512 threads = 8 waves (2 wave-rows x 4 wave-cols). Per-wave output 128x64 = acc[8][4], 16x16x32.
// LDS 128KB: Abuf[2]@0 (2x32KB) + Bbuf[2]@64KB (2x32KB). Tile = [256 rows][64 k] bf16, 128B rows.
// Swizzle (T2): 16B chunk c stored at c^(row&7); inverse-swizzled global source + linear
//   global_load_lds dest (rule #21). Fragment read (16 rows x 4 chunks) = 0 conflicts (R3-R13).
// Iteration it handles tiles 2it (buf0), 2it+1 (buf1); 8 phases, each:
//   {4-8 DSR (base reg + imm, zero VALU) | 1 half-tile stage (2 gloads) | BAR |
//    lgkm(0)+SB0 | setprio(1) | 16 MFMA | setprio(0) | BAR}
// Reads drain during the barrier wait. Stage slots (R4-verified ledger):
//   P1/P2: A(2it+1) halves -> buf1 ; P3/P4: B(2it+2) halves -> buf0 ;
//   P5/P6: A(2it+2) halves -> buf0 ; P7/P8: B(2it+3) halves -> buf1.
// vmcnt(4) only at P4 / P8 (T4: never 0 in-loop): retires consumed tile's 8 loads,
//   leaves next B's 4 flying. B-frags (Br0/Br1) register-cached across mh-halves.

template<int LD, int NTK, int NTILES, class Epi>
__device__ void mfma8(const unsigned short* __restrict__ Ag,
                      const unsigned short* __restrict__ Bg,
                      int m0base, int n0, int t,
                      unsigned short* lds, Epi epi)
{
    constexpr int TOT = NTK * NTILES;       // even
    constexpr int NI  = TOT / 2;
    const int lane = t & 63, wid = t >> 6;
    const int wr = wid >> 2, wc = wid & 3;            // 2M x 4N wave grid
    const int cl = lane & 15, hi = lane >> 4;
    const int Lb = (int)(size_t)(__attribute__((address_space(3))) unsigned short*)lds;
    const int swz = ((hi ^ (cl & 7)) << 4);
    // loop-invariant LDS base registers (bytes): buf0/buf1 x ks0/ks1
    const int aof0  = Lb + (wr * 128 + cl) * 128 + swz;
    const int aof1  = aof0 + 32768;
    const int aof0x = aof0 ^ 64;
    const int aof1x = aof1 ^ 64;
    const int bof0  = Lb + 65536 + (wc * 64 + cl) * 128 + swz;
    const int bof1  = bof0 + 32768;
    const int bof0x = bof0 ^ 64;
    const int bof1x = bof1 ^ 64;
    const int srow = t >> 3;
    const int schk = ((t & 7) ^ (srow & 7)) * 8;      // shorts
    const int sdst = t * 16;                          // bytes
    char* const L = (char*)lds;

#define STGAH(f, h, buf) { const int ot_ = (f) / NTK, kt_ = (f) % NTK; \
    const unsigned short* g_ = Ag + (size_t)(m0base + ot_ * 256 + (h) * 128 + srow) * LD + kt_ * 64 + schk; \
    char* d_ = L + (buf) * 32768 + (h) * 16384 + sdst; \
    gload16(g_, d_); gload16(g_ + (size_t)64 * LD, d_ + 8192); }
#define STGBH(f, h, buf) { const int kt_ = (f) % NTK; \
    const unsigned short* g_ = Bg + (size_t)(n0 + (h) * 128 + srow) * LD + kt_ * 64 + schk; \
    char* d_ = L + 65536 + (buf) * 32768 + (h) * 16384 + sdst; \
    gload16(g_, d_); gload16(g_ + (size_t)64 * LD, d_ + 8192); }
#define RDB(dst, bof) { DSR(dst[0], bof, "0"); DSR(dst[1], bof, "2048"); \
    DSR(dst[2], bof, "4096"); DSR(dst[3], bof, "6144"); }
#define RDA0(dst, aof) { DSR(dst[0], aof, "0"); DSR(dst[1], aof, "2048"); \
    DSR(dst[2], aof, "4096"); DSR(dst[3], aof, "6144"); }
#define RDA1(dst, aof) { DSR(dst[0], aof, "8192"); DSR(dst[1], aof, "10240"); \
    DSR(dst[2], aof, "12288"); DSR(dst[3], aof, "14336"); }
#define MM(mb, Arr, Brr) { __builtin_amdgcn_s_setprio(1); \
    _Pragma("unroll") for (int mf = 0; mf < 4; ++mf) \
    _Pragma("unroll") for (int nf = 0; nf < 4; ++nf) \
        acc[(mb) + mf][nf] = __builtin_amdgcn_mfma_f32_16x16x32_bf16(Arr[mf], Brr[nf], acc[(mb) + mf][nf], 0, 0, 0); \
    __builtin_amdgcn_s_setprio(0); }

    f32x4 acc[8][4];
    #pragma unroll
    for (int i = 0; i < 8; ++i)
        #pragma unroll
        for (int j = 0; j < 4; ++j) acc[i][j] = (f32x4)0.f;

    // prologue: tile0 -> buf0 (A 4 + B 4 gloads), tile1.B -> buf1 (4 gloads)
    STGAH(0, 0, 0); STGAH(0, 1, 0);
    STGBH(0, 0, 0); STGBH(0, 1, 0);
    STGBH(1, 0, 1); STGBH(1, 1, 1);
    VMC(4);                                  // tile0 landed; tile1.B flying
    BAR();

    bf16x8 Br0[4], Br1[4], Ar[4];

    for (int it = 0; it < NI; ++it) {
        const int f1 = 2 * it + 1;
        int t2 = 2 * it + 2; if (t2 > TOT - 1) t2 = TOT - 1;
        int t3 = 2 * it + 3; if (t3 > TOT - 1) t3 = TOT - 1;

        // ---- tile 2it (buf0) ----
        // P1 (mh0, ks0)
        RDB(Br0, bof0); RDA0(Ar, aof0);
        STGAH(f1, 0, 1);
        BAR(); LGKM0();
        MM(0, Ar, Br0);
        BAR();
        // P2 (mh0, ks1)
        RDB(Br1, bof0x); RDA0(Ar, aof0x);
        STGAH(f1, 1, 1);
        BAR(); LGKM0();
        MM(0, Ar, Br1);
        BAR();
        // P3 (mh1, ks0)
        RDA1(Ar, aof0);
        STGBH(t2, 0, 0);
        BAR(); LGKM0();
        MM(4, Ar, Br0);
        BAR();
        // P4 (mh1, ks1)
        RDA1(Ar, aof0x);
        STGBH(t2, 1, 0);
        VMC(4);                              // tile 2it+1 fully landed; B(t2) flying
        BAR(); LGKM0();
        MM(4, Ar, Br1);
        BAR();

        // ---- tile 2it+1 (buf1) ----
        // P5 (mh0, ks0)
        RDB(Br0, bof1); RDA0(Ar, aof1);
        STGAH(t2, 0, 0);
        BAR(); LGKM0();
        MM(0, Ar, Br0);
        BAR();
        // P6 (mh0, ks1)
        RDB(Br1, bof1x); RDA0(Ar, aof1x);
        STGAH(t2, 1, 0);
        BAR(); LGKM0();
        MM(0, Ar, Br1);
        BAR();
        // P7 (mh1, ks0)
        RDA1(Ar, aof1);
        STGBH(t3, 0, 1);
        BAR(); LGKM0();
        MM(4, Ar, Br0);
        BAR();
        // P8 (mh1, ks1)
        RDA1(Ar, aof1x);
        STGBH(t3, 1, 1);
        VMC(4);                              // tile t2 fully landed; B(t3) flying
        BAR(); LGKM0();
        MM(4, Ar, Br1);
        BAR();

        if ((f1 % NTK) == NTK - 1) {         // m-tile boundary
            epi(f1 / NTK, acc);
            #pragma unroll
            for (int i = 0; i < 8; ++i)
                #pragma unroll
                for (int j = 0; j < 4; ++j) acc[i][j] = (f32x4)0.f;
        }
    }
    asm volatile("s_waitcnt vmcnt(0)" ::: "memory");  // drain tail junk stages

#undef STGAH
#undef STGBH
#undef RDB
#undef RDA0
#undef RDA1
#undef MM
}

// gates GEMM: A [16384][2048] bf16, WT [4096][2048] bf16 (gate-interleaved cols).
// grid 256 = 1 block/CU; each block chains 4 m-tiles at fixed n-panel.
__global__ __launch_bounds__(512, 2)
void gemm_gates(const unsigned short* __restrict__ A, const unsigned short* __restrict__ WT,
                const float* __restrict__ bsum,
                const float* __restrict__ c_prev, const float* __restrict__ n_prev,
                float* __restrict__ out_h, float* __restrict__ out_C, float* __restrict__ out_n,
                unsigned short* __restrict__ h_bf)
{
    __shared__ unsigned short lds[65536];   // 128 KB
    const int t = threadIdx.x;
    const int b = blockIdx.x;               // 256 blocks
    const int nb  = (b & 7) * 2 + (b >> 7);         // 0..15 ; each XCD holds 2 n-panels in L2
    const int mb0 = ((b >> 3) & 15) * 4;            // m-tiles mb0..mb0+3
    const int m0base = mb0 * 256;
    const int n0 = nb * 256;                        // c'-space

    const int lane = t & 63, wid = t >> 6;
    const int wr = wid >> 2, wc = wid & 3;
    const int cl = lane & 15, hi = lane >> 4;
    const int j_out = nb * 64 + wc * 16 + cl;       // output column 0..1023
    const float bz_ = bsum[j_out];
    const float bi_ = bsum[1024 + j_out];
    const float bf_ = bsum[2048 + j_out];
    const float bo_ = bsum[3072 + j_out];

    auto epi = [&](int ot, f32x4 (&acc)[8][4]) {
        #pragma unroll
        for (int mf = 0; mf < 8; ++mf) {
            const int rb = m0base + ot * 256 + wr * 128 + mf * 16 + hi * 4;
            #pragma unroll
            for (int r = 0; r < 4; ++r) {
                const size_t idx = (size_t)(rb + r) * 1024 + j_out;
                const float pz = acc[mf][0][r] + bz_;
                const float pi = acc[mf][1][r] + bi_;
                const float pf = acc[mf][2][r] + bf_;
                const float po = acc[mf][3][r] + bo_;
                const float zt = tanh_f(pz);
                const float it = __expf(pi);
                const float ft = sigm_f(pf);
                const float ot_ = sigm_f(po);
                const float Cv = ft * c_prev[idx] + it * zt;
                const float nv = ft * n_prev[idx] + it;
                const float hv = ot_ * tanh_f(Cv / (nv + EPSv));
                __builtin_nontemporal_store(hv, &out_h[idx]);
                __builtin_nontemporal_store(Cv, &out_C[idx]);
                __builtin_nontemporal_store(nv, &out_n[idx]);
                h_bf[idx] = f2bf(hv);
            }
        }
    };

    mfma8<2048, 32, 4>(A, WT, m0base, n0, t, lds, epi);
}

// y GEMM: h_bf [16384][1024] @ WyT^T + by -> y [16384][1024] f32. grid 256, 1 tile/block.
__global__ __launch_bounds__(512, 2)
void gemm_y(const unsigned short* __restrict__ A, const unsigned short* __restrict__ WyT,
            const float* __restrict__ by, float* __restrict__ y)
{
    __shared__ unsigned short lds[65536];
    const int t = threadIdx.x;
    const int b = blockIdx.x;               // 256 = 64 mb x 4 nb
    const int nb = b & 3, mb = b >> 2;
    const int m0base = mb * 256, n0 = nb * 256;

    const int lane = t & 63, wid = t >> 6;
    const int wr = wid >> 2, wc = wid & 3;
    const int cl = lane & 15, hi = lane >> 4;

    auto epi = [&](int ot, f32x4 (&acc)[8][4]) {
        (void)ot;
        #pragma unroll
        for (int mf = 0; mf < 8; ++mf) {
            const int rb = m0base + wr * 128 + mf * 16 + hi * 4;
            #pragma unroll
            for (int nf = 0; nf < 4; ++nf) {
                const int c = n0 + wc * 64 + nf * 16 + cl;
                const float bc = by[c];
                #pragma unroll
                for (int r = 0; r < 4; ++r)
                    __builtin_nontemporal_store(acc[mf][nf][r] + bc, &y[(size_t)(rb + r) * 1024 + c]);
            }
        }
    };

    mfma8<1024, 16, 1>(A, WyT, m0base, n0, t, lds, epi);
}

// ---------------- fallback f32 path (round-1 kernels) ----------------

constexpr int FBM = 64, FBN = 64, FBK = 16, FPAD = 4;

__global__ __launch_bounds__(256)
void fb_gates(const float* __restrict__ x, const float* __restrict__ h_prev,
              const float* __restrict__ c_prev, const float* __restrict__ n_prev,
              const float* __restrict__ Wz, const float* __restrict__ Rz,
              const float* __restrict__ Wi, const float* __restrict__ Ri,
              const float* __restrict__ Wf, const float* __restrict__ Rf,
              const float* __restrict__ Wo, const float* __restrict__ Ro,
              const float* __restrict__ bWz, const float* __restrict__ bRz, const float* __restrict__ bz,
              const float* __restrict__ bWi, const float* __restrict__ bRi, const float* __restrict__ bi,
              const float* __restrict__ bWf, const float* __restrict__ bRf, const float* __restrict__ bf_,
              const float* __restrict__ bWo, const float* __restrict__ bRo, const float* __restrict__ bo,
              float* __restrict__ out_h, float* __restrict__ out_C, float* __restrict__ out_n)
{
    __shared__ float sA[FBK][FBM + FPAD];
    __shared__ float sB[4][FBK][FBN + FPAD];
    const int t = threadIdx.x;
    const int col_blk = blockIdx.x & 15, row_blk = blockIdx.x >> 4;
    const int row0 = row_blk * FBM, col0 = col_blk * FBN;
    const int tx = t & 15, ty = t >> 4;
    float acc[4][4][4];
    #pragma unroll
    for (int g = 0; g < 4; ++g)
        for (int i = 0; i < 4; ++i)
            for (int j = 0; j < 4; ++j) acc[g][i][j] = 0.f;
    const int ar = t >> 2, ak = (t & 3) * 4, wk = t >> 4, wcc = (t & 15) * 4;
    for (int phase = 0; phase < 2; ++phase) {
        const float* Am = phase ? h_prev : x;
        const float* W0 = phase ? Rz : Wz; const float* W1 = phase ? Ri : Wi;
        const float* W2 = phase ? Rf : Wf; const float* W3 = phase ? Ro : Wo;
        for (int k0 = 0; k0 < 1024; k0 += FBK) {
            __syncthreads();
            {
                const float4 v = *(const float4*)(Am + (size_t)(row0 + ar) * 1024 + k0 + ak);
                sA[ak + 0][ar] = v.x; sA[ak + 1][ar] = v.y;
                sA[ak + 2][ar] = v.z; sA[ak + 3][ar] = v.w;
            }
            *(float4*)&sB[0][wk][wcc] = *(const float4*)(W0 + (size_t)(k0 + wk) * 1024 + col0 + wcc);
            *(float4*)&sB[1][wk][wcc] = *(const float4*)(W1 + (size_t)(k0 + wk) * 1024 + col0 + wcc);
            *(float4*)&sB[2][wk][wcc] = *(const float4*)(W2 + (size_t)(k0 + wk) * 1024 + col0 + wcc);
            *(float4*)&sB[3][wk][wcc] = *(const float4*)(W3 + (size_t)(k0 + wk) * 1024 + col0 + wcc);
            __syncthreads();
            #pragma unroll
            for (int kk = 0; kk < FBK; ++kk) {
                float a[4], bb[4][4];
                *(float4*)a = *(const float4*)&sA[kk][ty * 4];
                *(float4*)&bb[0][0] = *(const float4*)&sB[0][kk][tx * 4];
                *(float4*)&bb[1][0] = *(const float4*)&sB[1][kk][tx * 4];
                *(float4*)&bb[2][0] = *(const float4*)&sB[2][kk][tx * 4];
                *(float4*)&bb[3][0] = *(const float4*)&sB[3][kk][tx * 4];
                #pragma unroll
                for (int g = 0; g < 4; ++g)
                    for (int i = 0; i < 4; ++i)
                        for (int j = 0; j < 4; ++j)
                            acc[g][i][j] += a[i] * bb[g][j];
            }
        }
    }
    #pragma unroll
    for (int i = 0; i < 4; ++i) {
        const int r = row0 + ty * 4 + i;
        #pragma unroll
        for (int j = 0; j < 4; ++j) {
            const int c = col0 + tx * 4 + j;
            const float pz = acc[0][i][j] + bWz[c] + bRz[c] + bz[c];
            const float pi = acc[1][i][j] + bWi[c] + bRi[c] + bi[c];
            const float pf = acc[2][i][j] + bWf[c] + bRf[c] + bf_[c];
            const float po = acc[3][i][j] + bWo[c] + bRo[c] + bo[c];
            const float zt = tanhf(pz);
            const float it = expf(pi);
            const float ft = 1.f / (1.f + expf(-pf));
            const float ot = 1.f / (1.f + expf(-po));
            const size_t idx = (size_t)r * Hh + c;
            const float Cv = ft * c_prev[idx] + it * zt;
            const float nv = ft * n_prev[idx] + it;
            out_h[idx] = ot * tanhf(Cv / (nv + EPSv));
            out_C[idx] = Cv;
            out_n[idx] = nv;
        }
    }
}

__global__ __launch_bounds__(256)
void fb_ygemm(const float* __restrict__ hmat, const float* __restrict__ Wy,
              const float* __restrict__ by, float* __restrict__ y)
{
    __shared__ float sA[FBK][FBM + FPAD];
    __shared__ float sB[FBK][FBN + FPAD];
    const int t = threadIdx.x;
    const int col_blk = blockIdx.x & 15, row_blk = blockIdx.x >> 4;
    const int row0 = row_blk * FBM, col0 = col_blk * FBN;
    const int tx = t & 15, ty = t >> 4;
    float acc[4][4];
    #pragma unroll
    for (int i = 0; i < 4; ++i)
        for (int j = 0; j < 4; ++j) acc[i][j] = 0.f;
    const int ar = t >> 2, ak = (t & 3) * 4, wk = t >> 4, wcc = (t & 15) * 4;
    for (int k0 = 0; k0 < 1024; k0 += FBK) {
        __syncthreads();
        {
            const float4 v = *(const float4*)(hmat + (size_t)(row0 + ar) * 1024 + k0 + ak);
            sA[ak + 0][ar] = v.x; sA[ak + 1][ar] = v.y;
            sA[ak + 2][ar] = v.z; sA[ak + 3][ar] = v.w;
        }
        *(float4*)&sB[wk][wcc] = *(const float4*)(Wy + (size_t)(k0 + wk) * 1024 + col0 + wcc);
        __syncthreads();
        #pragma unroll
        for (int kk = 0; kk < FBK; ++kk) {
            float a[4], bb[4];
            *(float4*)a = *(const float4*)&sA[kk][ty * 4];
            *(float4*)bb = *(const float4*)&sB[kk][tx * 4];
            #pragma unroll
            for (int i = 0; i < 4; ++i)
                for (int j = 0; j < 4; ++j)
                    acc[i][j] += a[i] * bb[j];
        }
    }
    #pragma unroll
    for (int i = 0; i < 4; ++i) {
        const int r = row0 + ty * 4 + i;
        #pragma unroll
        for (int j = 0; j < 4; ++j) {
            const int c = col0 + tx * 4 + j;
            y[(size_t)r * Dd + c] = acc[i][j] + by[c];
        }
    }
}

// ---------------- launch ----------------

extern "C" void kernel_launch(void* const* d_in, const int* in_sizes, int n_in,
                              void* d_out, int out_size, void* d_ws, size_t ws_size,
                              hipStream_t stream) {
    const float* x      = (const float*)d_in[0];
    const float* h_prev = (const float*)d_in[1];
    const float* c_prev = (const float*)d_in[2];
    const float* n_prev = (const float*)d_in[3];
    const float* Wz  = (const float*)d_in[4];
    const float* bWz = (const float*)d_in[5];
    const float* Rz  = (const float*)d_in[6];
    const float* bRz = (const float*)d_in[7];
    const float* bz  = (const float*)d_in[8];
    const float* Wi  = (const float*)d_in[9];
    const float* bWi = (const float*)d_in[10];
    const float* Ri  = (const float*)d_in[11];
    const float* bRi = (const float*)d_in[12];
    const float* bi  = (const float*)d_in[13];
    const float* Wf  = (const float*)d_in[14];
    const float* bWf = (const float*)d_in[15];
    const float* Rf  = (const float*)d_in[16];
    const float* bRf = (const float*)d_in[17];
    const float* bf_ = (const float*)d_in[18];
    const float* Wo  = (const float*)d_in[19];
    const float* bWo = (const float*)d_in[20];
    const float* Ro  = (const float*)d_in[21];
    const float* bRo = (const float*)d_in[22];
    const float* bo  = (const float*)d_in[23];
    const float* Wy  = (const float*)d_in[24];
    const float* by  = (const float*)d_in[25];

    float* y     = (float*)d_out;
    float* out_h = y + (size_t)Bsz * Dd;
    float* out_C = out_h + (size_t)Bsz * Hh;
    float* out_n = out_C + (size_t)Bsz * Hh;

    // ws layout (bytes)
    const size_t OFF_A    = 0;           // 16384*2048*2 = 67108864
    const size_t OFF_WT   = 67108864;    // 4096*2048*2  = 16777216
    const size_t OFF_WYT  = 83886080;    // 1024*1024*2  = 2097152
    const size_t OFF_HBF  = 85983232;    // 16384*1024*2 = 33554432
    const size_t OFF_BS   = 119537664;   // 4*1024*4     = 16384
    const size_t WS_NEED  = 119554048;

    if (ws_size >= WS_NEED) {
        char* ws = (char*)d_ws;
        unsigned short* A_bf = (unsigned short*)(ws + OFF_A);
        unsigned short* WT   = (unsigned short*)(ws + OFF_WT);
        unsigned short* WyT  = (unsigned short*)(ws + OFF_WYT);
        unsigned short* h_bf = (unsigned short*)(ws + OFF_HBF);
        float* bsum          = (float*)(ws + OFF_BS);

        CvtArgs P;
        P.x = x; P.hp = h_prev; P.abf = A_bf;
        P.src[0] = Wz; P.src[1] = Rz; P.src[2] = Wi; P.src[3] = Ri;
        P.src[4] = Wf; P.src[5] = Rf; P.src[6] = Wo; P.src[7] = Ro; P.src[8] = Wy;
        P.bptr[0] = bWz; P.bptr[1] = bRz; P.bptr[2]  = bz;
        P.bptr[3] = bWi; P.bptr[4] = bRi; P.bptr[5]  = bi;
        P.bptr[6] = bWf; P.bptr[7] = bRf; P.bptr[8]  = bf_;
        P.bptr[9] = bWo; P.bptr[10] = bRo; P.bptr[11] = bo;
        P.wt = WT; P.wyt = WyT; P.bs = bsum;
        cvt_all<<<18692, 256, 0, stream>>>(P);

        gemm_gates<<<256, 512, 0, stream>>>(A_bf, WT, bsum, c_prev, n_prev,
                                            out_h, out_C, out_n, h_bf);
        gemm_y<<<256, 512, 0, stream>>>(h_bf, WyT, by, y);
    } else {
        dim3 block(256);
        dim3 grid((Bsz / FBM) * (Hh / FBN));
        fb_gates<<<grid, block, 0, stream>>>(x, h_prev, c_prev, n_prev,
                                             Wz, Rz, Wi, Ri, Wf, Rf, Wo, Ro,
                                             bWz, bRz, bz, bWi, bRi, bi,
                                             bWf, bRf, bf_, bWo, bRo, bo,
                                             out_h, out_C, out_n);
        fb_ygemm<<<grid, block, 0, stream>>>(out_h, Wy, by, y);
    }
}